// Round 3
// baseline (4656.870 us; speedup 1.0000x reference)
//
#include <hip/hip_runtime.h>
#include <stdint.h>

#define T_SEQ 512
#define BATCH 256
#define HID   128
#define G4    512   // 4*H
#define XD    257
#define ZD    16

typedef short  bf16x8 __attribute__((ext_vector_type(8)));
typedef float  f32x4  __attribute__((ext_vector_type(4)));

#define MFMA(a,b,c) __builtin_amdgcn_mfma_f32_16x16x32_bf16((a),(b),(c),0,0,0)

// packed B-fragment segment offsets (uint4 units)
#define OHH_GX 0
#define OHH_GZ 8192
#define OHH_H  16384
#define OIH_GZ 24576
#define OIH_H  26624
#define OW0    28672
#define OWM    32768
#define OWV    33024
#define NPACK  33280

// ---------- helpers ----------
__device__ __forceinline__ float bf2f(uint16_t u) {
  union { uint32_t i; float f; } v; v.i = ((uint32_t)u) << 16; return v.f;
}
__device__ __forceinline__ uint16_t f2bf(float f) {
  union { float f; uint32_t i; } v; v.f = f;
  uint32_t r = v.i + 0x7fffu + ((v.i >> 16) & 1u);
  return (uint16_t)(r >> 16);
}
__device__ __forceinline__ float tanhfast(float x) { return 2.0f / (1.0f + __expf(-2.0f * x)) - 1.0f; }
__device__ __forceinline__ float gate_act(float pre, bool isg) {
  float s = isg ? (-2.0f * pre) : (-pre);
  float r = 1.0f / (1.0f + __expf(s));
  return isg ? (2.0f * r - 1.0f) : r;
}

// ---------- kernel 1: weight transposes for k_proj / k_y ----------
__global__ void k_prep(const float* __restrict__ Wih_gx, const float* __restrict__ Wy,
                       float* __restrict__ wT, float* __restrict__ wyT) {
  int idx = blockIdx.x * 256 + threadIdx.x;
  const int N1 = XD * G4;          // 131584
  const int N2 = HID * XD;         // 32896
  if (idx < N1) {
    int j = idx & (G4 - 1), d = idx >> 9;       // wT[d*512+j] = Wih_gx[j*257+d]
    wT[idx] = Wih_gx[j * XD + d];
  } else if (idx < N1 + N2) {
    int i2 = idx - N1;
    int u = i2 / XD, d = i2 % XD;               // wyT[u*257+d] = Wy[d*128+u]
    wyT[i2] = Wy[d * HID + u];
  }
}

// ---------- kernel 1b: pack weights into MFMA B-fragments (bf16) ----------
// B[k][n] = W[row(n)][k]; frag layout: [(tile*KT + kt)*64 + lane] = 8 bf16,
// n = tile*16 + (lane&15), k = kt*32 + (lane>>4)*8 + j.
// perm (512-col LSTM weights): row = (tile&3)*128 + (tile>>2)*16 + (lane&15)
__global__ __launch_bounds__(256) void k_pack(
    const float* __restrict__ Whh_gx, const float* __restrict__ Whh_gz,
    const float* __restrict__ Whh_h,  const float* __restrict__ Wih_gz,
    const float* __restrict__ Wih_h,  const float* __restrict__ W0,
    const float* __restrict__ Wm,     const float* __restrict__ Wv,
    uint4* __restrict__ out) {
  int idx = blockIdx.x * 256 + threadIdx.x;
  if (idx >= NPACK) return;
  const float* W; int Kreal, KT, base; bool perm;
  if      (idx < OHH_GZ) { W = Whh_gx; Kreal = 128; KT = 4; perm = true;  base = OHH_GX; }
  else if (idx < OHH_H ) { W = Whh_gz; Kreal = 128; KT = 4; perm = true;  base = OHH_GZ; }
  else if (idx < OIH_GZ) { W = Whh_h;  Kreal = 128; KT = 4; perm = true;  base = OHH_H;  }
  else if (idx < OIH_H ) { W = Wih_gz; Kreal = 16;  KT = 1; perm = true;  base = OIH_GZ; }
  else if (idx < OW0   ) { W = Wih_h;  Kreal = 16;  KT = 1; perm = true;  base = OIH_H;  }
  else if (idx < OWM   ) { W = W0;     Kreal = 256; KT = 8; perm = false; base = OW0;    }
  else if (idx < OWV   ) { W = Wm;     Kreal = 128; KT = 4; perm = false; base = OWM;    }
  else                   { W = Wv;     Kreal = 128; KT = 4; perm = false; base = OWV;    }
  int li = idx - base;
  int lane = li & 63, rest = li >> 6;
  int kt = rest % KT, tile = rest / KT;
  int n15 = lane & 15, quad = lane >> 4;
  int r = perm ? ((tile & 3) * 128 + (tile >> 2) * 16 + n15) : (tile * 16 + n15);
  int k0 = kt * 32 + quad * 8;
  uint16_t v[8];
#pragma unroll
  for (int j = 0; j < 8; ++j) {
    float f = (k0 + j < Kreal) ? W[(size_t)r * Kreal + k0 + j] : 0.0f;
    v[j] = f2bf(f);
  }
  uint4 o4;
  o4.x = (uint32_t)v[0] | ((uint32_t)v[1] << 16);
  o4.y = (uint32_t)v[2] | ((uint32_t)v[3] << 16);
  o4.z = (uint32_t)v[4] | ((uint32_t)v[5] << 16);
  o4.w = (uint32_t)v[6] | ((uint32_t)v[7] << 16);
  out[idx] = o4;
}

// ---------- kernel 2: px[t][b][j] = b_ih+b_hh + sum_d x[b][d][t]*Wih_gx[j][d] (bf16) ----------
__global__ __launch_bounds__(256) void k_proj(
    const float* __restrict__ x, const float* __restrict__ wT,
    const float* __restrict__ bih, const float* __restrict__ bhh,
    uint16_t* __restrict__ px) {
  __shared__ uint16_t xs[XD * 66];
  int tid = threadIdx.x;
  int t0 = blockIdx.x * 64, b = blockIdx.y;
  int lane = tid & 63;
  {
    int t = tid & 63, d0 = tid >> 6;
    for (int d = d0; d < XD; d += 4)
      xs[d * 66 + t] = f2bf(x[((size_t)b * XD + d) * T_SEQ + t0 + t]);
  }
  __syncthreads();
  int w = __builtin_amdgcn_readfirstlane(tid >> 6);
  for (int p = 0; p < 8; ++p) {
    int j0 = w * 128 + p * 16;
    float acc[16];
#pragma unroll
    for (int i = 0; i < 16; ++i) acc[i] = bih[j0 + i] + bhh[j0 + i];
    for (int d = 0; d < XD; ++d) {
      float xv = bf2f(xs[d * 66 + lane]);
      const float* wrow = wT + (size_t)d * G4 + j0;
#pragma unroll
      for (int i = 0; i < 16; ++i) acc[i] = fmaf(wrow[i], xv, acc[i]);
    }
    size_t base = ((size_t)(t0 + lane) * BATCH + b) * G4 + j0;
    uint32_t pkd[8];
#pragma unroll
    for (int i = 0; i < 8; ++i)
      pkd[i] = (uint32_t)f2bf(acc[2 * i]) | ((uint32_t)f2bf(acc[2 * i + 1]) << 16);
    uint4* dst = (uint4*)(px + base);
    dst[0] = make_uint4(pkd[0], pkd[1], pkd[2], pkd[3]);
    dst[1] = make_uint4(pkd[4], pkd[5], pkd[6], pkd[7]);
  }
}

// ---------- kernel 3: backward LSTM g_x — MFMA over 16 batch rows/block ----------
__global__ __launch_bounds__(512, 2) void k_lstm_gx(
    const uint16_t* __restrict__ px, const uint4* __restrict__ pk,
    uint16_t* __restrict__ gx) {
  __shared__ uint16_t hl[2][16 * 136];
  int tid = threadIdx.x, b0 = blockIdx.x * 16;
  int lane = tid & 63, w = tid >> 6;
  int n15 = lane & 15, quad = lane >> 4;
  const bf16x8* pkb = (const bf16x8*)pk;
  bf16x8 whh[4][4];
#pragma unroll
  for (int ct = 0; ct < 4; ++ct)
#pragma unroll
    for (int kt = 0; kt < 4; ++kt)
      whh[ct][kt] = pkb[OHH_GX + ((4 * w + ct) * 4 + kt) * 64 + lane];
  for (int i = tid; i < 16 * 136; i += 512) hl[0][i] = 0;
  float c[4] = {0.f, 0.f, 0.f, 0.f};
  int cur = 0;
  uint16_t pxr[4][4];
#pragma unroll
  for (int ct = 0; ct < 4; ++ct) {
    int r = ct * 128 + w * 16 + n15;
#pragma unroll
    for (int reg = 0; reg < 4; ++reg)
      pxr[ct][reg] = px[((size_t)(T_SEQ - 1) * BATCH + b0 + quad * 4 + reg) * G4 + r];
  }
  __syncthreads();
  for (int t = T_SEQ - 1; t >= 0; --t) {
    bf16x8 a[4];
#pragma unroll
    for (int kt = 0; kt < 4; ++kt)
      a[kt] = *(const bf16x8*)&hl[cur][n15 * 136 + kt * 32 + quad * 8];
    // prefetch next-t px
    int tn = t > 0 ? t - 1 : 0;
    uint16_t pxn[4][4];
#pragma unroll
    for (int ct = 0; ct < 4; ++ct) {
      int r = ct * 128 + w * 16 + n15;
#pragma unroll
      for (int reg = 0; reg < 4; ++reg)
        pxn[ct][reg] = px[((size_t)tn * BATCH + b0 + quad * 4 + reg) * G4 + r];
    }
    float act[4][4];
#pragma unroll
    for (int ct = 0; ct < 4; ++ct) {
      f32x4 acc = {bf2f(pxr[ct][0]), bf2f(pxr[ct][1]), bf2f(pxr[ct][2]), bf2f(pxr[ct][3])};
#pragma unroll
      for (int kt = 0; kt < 4; ++kt) acc = MFMA(a[kt], whh[ct][kt], acc);
#pragma unroll
      for (int reg = 0; reg < 4; ++reg) act[ct][reg] = gate_act(acc[reg], ct == 2);
    }
#pragma unroll
    for (int reg = 0; reg < 4; ++reg) {
      c[reg] = act[1][reg] * c[reg] + act[0][reg] * act[2][reg];
      float h = act[3][reg] * tanhfast(c[reg]);
      uint16_t hb = f2bf(h);
      int m = quad * 4 + reg;
      hl[cur ^ 1][m * 136 + w * 16 + n15] = hb;
      gx[((size_t)t * BATCH + b0 + m) * HID + w * 16 + n15] = hb;
    }
#pragma unroll
    for (int ct = 0; ct < 4; ++ct)
#pragma unroll
      for (int reg = 0; reg < 4; ++reg) pxr[ct][reg] = pxn[ct][reg];
    cur ^= 1;
    __syncthreads();
  }
}

// ---------- kernel 4: fused inference — MFMA over 16 batch rows/block ----------
__global__ __launch_bounds__(512, 2) void k_inf(
    const uint16_t* __restrict__ gx, const float* __restrict__ eps,
    const uint4* __restrict__ pk,
    const float* __restrict__ bih_gz, const float* __restrict__ bhh_gz,
    const float* __restrict__ b0, const float* __restrict__ bm,
    const float* __restrict__ bv,
    uint16_t* __restrict__ zbuf, float* __restrict__ out_mean,
    float* __restrict__ out_logvar, float* __restrict__ out_z) {
  __shared__ uint16_t gzl[2][16 * 136];
  __shared__ uint16_t hmlp[16 * 136];
  __shared__ uint16_t zt[16 * 40];
  __shared__ float means[16 * 17];
  __shared__ float lvs[16 * 17];
  int tid = threadIdx.x, b0i = blockIdx.x * 16;
  int lane = tid & 63, w = tid >> 6;
  int n15 = lane & 15, quad = lane >> 4;
  const bf16x8* pkb = (const bf16x8*)pk;
  bf16x8 w0f[8];
#pragma unroll
  for (int kt = 0; kt < 8; ++kt) w0f[kt] = pkb[OW0 + (w * 8 + kt) * 64 + lane];
  bf16x8 whz[4][4];
#pragma unroll
  for (int ct = 0; ct < 4; ++ct)
#pragma unroll
    for (int kt = 0; kt < 4; ++kt)
      whz[ct][kt] = pkb[OHH_GZ + ((4 * w + ct) * 4 + kt) * 64 + lane];
  float bzr[4];
#pragma unroll
  for (int ct = 0; ct < 4; ++ct) {
    int r = ct * 128 + w * 16 + n15;
    bzr[ct] = bih_gz[r] + bhh_gz[r];
  }
  float b0r = b0[w * 16 + n15];
  float bmvr = (w == 0) ? bm[n15] : ((w == 1) ? bv[n15] : 0.0f);
  for (int i = tid; i < 16 * 136; i += 512) gzl[0][i] = 0;
  for (int i = tid; i < 16 * 40; i += 512) zt[i] = 0;
  float c[4] = {0.f, 0.f, 0.f, 0.f};
  int cur = 0;
  int zm = tid >> 4, zo = tid & 15;
  float epr = (tid < 256) ? eps[(size_t)(b0i + zm) * ZD + zo] : 0.0f;
  bf16x8 gxf[4];
#pragma unroll
  for (int kt = 0; kt < 4; ++kt)
    gxf[kt] = *(const bf16x8*)(gx + ((size_t)(b0i + n15)) * HID + kt * 32 + quad * 8);
  __syncthreads();
  for (int t = 0; t < T_SEQ; ++t) {
    // ---- stage B: h_mlp = tanh([gx|gz] @ W0^T + b0) ----
    bf16x8 gzf[4];
#pragma unroll
    for (int kt = 0; kt < 4; ++kt)
      gzf[kt] = *(const bf16x8*)&gzl[cur][n15 * 136 + kt * 32 + quad * 8];
    f32x4 hb = {b0r, b0r, b0r, b0r};
#pragma unroll
    for (int kt = 0; kt < 4; ++kt) hb = MFMA(gxf[kt], w0f[kt], hb);
#pragma unroll
    for (int kt = 0; kt < 4; ++kt) hb = MFMA(gzf[kt], w0f[4 + kt], hb);
    // prefetch next-t gx + eps
    int tn = (t < T_SEQ - 1) ? t + 1 : t;
    bf16x8 gxn[4];
#pragma unroll
    for (int kt = 0; kt < 4; ++kt)
      gxn[kt] = *(const bf16x8*)(gx + ((size_t)tn * BATCH + b0i + n15) * HID + kt * 32 + quad * 8);
    float epn = (tid < 256) ? eps[((size_t)tn * BATCH + b0i + zm) * ZD + zo] : 0.0f;
#pragma unroll
    for (int reg = 0; reg < 4; ++reg)
      hmlp[(quad * 4 + reg) * 136 + w * 16 + n15] = f2bf(tanhfast(hb[reg]));
    __syncthreads();  // b1
    // ---- stage C: mean (wave0) / logvar (wave1) ----
    if (w < 2) {
      f32x4 mac = {bmvr, bmvr, bmvr, bmvr};
#pragma unroll
      for (int kt = 0; kt < 4; ++kt) {
        bf16x8 ha = *(const bf16x8*)&hmlp[n15 * 136 + kt * 32 + quad * 8];
        bf16x8 wf = pkb[(w == 0 ? OWM : OWV) + kt * 64 + lane];
        mac = MFMA(ha, wf, mac);
      }
#pragma unroll
      for (int reg = 0; reg < 4; ++reg) {
        int m = quad * 4 + reg;
        if (w == 0) {
          means[m * 17 + n15] = mac[reg];
          out_mean[((size_t)(b0i + m) * ZD + n15) * T_SEQ + t] = mac[reg];
        } else {
          lvs[m * 17 + n15] = mac[reg];
          out_logvar[((size_t)(b0i + m) * ZD + n15) * T_SEQ + t] = mac[reg];
        }
      }
    }
    __syncthreads();  // b2
    // ---- stage Z: reparameterize ----
    if (tid < 256) {
      float mean = means[zm * 17 + zo], lv = lvs[zm * 17 + zo];
      float zv = epr * __expf(0.5f * lv) + mean;
      uint16_t zb = f2bf(zv);
      zt[zm * 40 + zo] = zb;
      zbuf[((size_t)t * BATCH + b0i + zm) * ZD + zo] = zb;
      out_z[((size_t)(b0i + zm) * ZD + zo) * T_SEQ + t] = zv;
    }
    __syncthreads();  // b3
    // ---- stage A: g_z LSTM cell ----
    bf16x8 za = *(const bf16x8*)&zt[n15 * 40 + quad * 8];
    float act[4][4];
#pragma unroll
    for (int ct = 0; ct < 4; ++ct) {
      f32x4 ga = {bzr[ct], bzr[ct], bzr[ct], bzr[ct]};
      bf16x8 wih = pkb[OIH_GZ + (4 * w + ct) * 64 + lane];
      ga = MFMA(za, wih, ga);
#pragma unroll
      for (int kt = 0; kt < 4; ++kt) ga = MFMA(gzf[kt], whz[ct][kt], ga);
#pragma unroll
      for (int reg = 0; reg < 4; ++reg) act[ct][reg] = gate_act(ga[reg], ct == 2);
    }
#pragma unroll
    for (int reg = 0; reg < 4; ++reg) {
      c[reg] = act[1][reg] * c[reg] + act[0][reg] * act[2][reg];
      float h = act[3][reg] * tanhfast(c[reg]);
      gzl[cur ^ 1][(quad * 4 + reg) * 136 + w * 16 + n15] = f2bf(h);
    }
#pragma unroll
    for (int kt = 0; kt < 4; ++kt) gxf[kt] = gxn[kt];
    epr = epn;
    cur ^= 1;
    __syncthreads();  // b4
  }
}

// ---------- kernel 5: decoder LSTM — MFMA over 16 batch rows/block ----------
__global__ __launch_bounds__(512, 2) void k_dec(
    const uint16_t* __restrict__ zbuf, const uint4* __restrict__ pk,
    const float* __restrict__ bih, const float* __restrict__ bhh,
    uint16_t* __restrict__ hdec) {
  __shared__ uint16_t gzl[2][16 * 136];
  __shared__ uint16_t zt[16 * 40];
  int tid = threadIdx.x, b0 = blockIdx.x * 16;
  int lane = tid & 63, w = tid >> 6;
  int n15 = lane & 15, quad = lane >> 4;
  const bf16x8* pkb = (const bf16x8*)pk;
  bf16x8 whh[4][4];
#pragma unroll
  for (int ct = 0; ct < 4; ++ct)
#pragma unroll
    for (int kt = 0; kt < 4; ++kt)
      whh[ct][kt] = pkb[OHH_H + ((4 * w + ct) * 4 + kt) * 64 + lane];
  bf16x8 wih[4];
#pragma unroll
  for (int ct = 0; ct < 4; ++ct) wih[ct] = pkb[OIH_H + (4 * w + ct) * 64 + lane];
  float bzr[4];
#pragma unroll
  for (int ct = 0; ct < 4; ++ct) {
    int r = ct * 128 + w * 16 + n15;
    bzr[ct] = bih[r] + bhh[r];
  }
  for (int i = tid; i < 16 * 136; i += 512) gzl[0][i] = 0;
  for (int i = tid; i < 16 * 40; i += 512) zt[i] = 0;
  float c[4] = {0.f, 0.f, 0.f, 0.f};
  int cur = 0;
  int zm = tid >> 4, zo = tid & 15;
  uint16_t zr = (tid < 256) ? zbuf[(size_t)(b0 + zm) * ZD + zo] : (uint16_t)0;
  __syncthreads();
  for (int t = 0; t < T_SEQ; ++t) {
    if (tid < 256) zt[zm * 40 + zo] = zr;
    __syncthreads();  // b1
    bf16x8 za = *(const bf16x8*)&zt[n15 * 40 + quad * 8];
    bf16x8 gzf[4];
#pragma unroll
    for (int kt = 0; kt < 4; ++kt)
      gzf[kt] = *(const bf16x8*)&gzl[cur][n15 * 136 + kt * 32 + quad * 8];
    // prefetch next z
    int tn = (t < T_SEQ - 1) ? t + 1 : t;
    uint16_t zn = (tid < 256) ? zbuf[((size_t)tn * BATCH + b0 + zm) * ZD + zo] : (uint16_t)0;
    float act[4][4];
#pragma unroll
    for (int ct = 0; ct < 4; ++ct) {
      f32x4 ga = {bzr[ct], bzr[ct], bzr[ct], bzr[ct]};
      ga = MFMA(za, wih[ct], ga);
#pragma unroll
      for (int kt = 0; kt < 4; ++kt) ga = MFMA(gzf[kt], whh[ct][kt], ga);
#pragma unroll
      for (int reg = 0; reg < 4; ++reg) act[ct][reg] = gate_act(ga[reg], ct == 2);
    }
#pragma unroll
    for (int reg = 0; reg < 4; ++reg) {
      c[reg] = act[1][reg] * c[reg] + act[0][reg] * act[2][reg];
      float h = act[3][reg] * tanhfast(c[reg]);
      uint16_t hb = f2bf(h);
      int m = quad * 4 + reg;
      gzl[cur ^ 1][m * 136 + w * 16 + n15] = hb;
      hdec[((size_t)t * BATCH + b0 + m) * HID + w * 16 + n15] = hb;
    }
    zr = zn;
    cur ^= 1;
    __syncthreads();  // b2
  }
}

// ---------- kernel 6: y = exp(hdec @ Wy.T + by), output (B, 257, T) ----------
__global__ __launch_bounds__(256) void k_y(
    const uint16_t* __restrict__ hdec, const float* __restrict__ wyT,
    const float* __restrict__ by, float* __restrict__ out_y) {
  __shared__ __align__(16) float hl[HID * 65];
  int tid = threadIdx.x;
  int t0 = blockIdx.x * 64, b = blockIdx.y;
  {
    int uu = tid & 127, tg = tid >> 7;
    for (int tt = tg; tt < 64; tt += 2)
      hl[uu * 65 + tt] = bf2f(hdec[((size_t)(t0 + tt) * BATCH + b) * HID + uu]);
  }
  __syncthreads();
  int w = __builtin_amdgcn_readfirstlane(tid >> 6);
  int lane = tid & 63;
  for (int p = 0; p < 4; ++p) {
    int d0 = w * 16 + p * 64;
    float acc[16];
#pragma unroll
    for (int i = 0; i < 16; ++i) acc[i] = by[d0 + i];
    for (int uu = 0; uu < HID; ++uu) {
      float hv = hl[uu * 65 + lane];
      const float* wrow = wyT + (size_t)uu * XD + d0;
#pragma unroll
      for (int i = 0; i < 16; ++i) acc[i] = fmaf(wrow[i], hv, acc[i]);
    }
#pragma unroll
    for (int i = 0; i < 16; ++i)
      out_y[((size_t)b * XD + d0 + i) * T_SEQ + t0 + lane] = __expf(acc[i]);
  }
  if (w == 0) {  // d = 256 tail
    float acc = by[256];
    for (int uu = 0; uu < HID; ++uu)
      acc = fmaf(wyT[(size_t)uu * XD + 256], hl[uu * 65 + lane], acc);
    out_y[((size_t)b * XD + 256) * T_SEQ + t0 + lane] = __expf(acc);
  }
}

extern "C" void kernel_launch(void* const* d_in, const int* in_sizes, int n_in,
                              void* d_out, int out_size, void* d_ws, size_t ws_size,
                              hipStream_t stream) {
  const float* x      = (const float*)d_in[0];
  const float* eps    = (const float*)d_in[1];
  const float* Wih_gx = (const float*)d_in[2];
  const float* Whh_gx = (const float*)d_in[3];
  const float* bih_gx = (const float*)d_in[4];
  const float* bhh_gx = (const float*)d_in[5];
  const float* Wih_gz = (const float*)d_in[6];
  const float* Whh_gz = (const float*)d_in[7];
  const float* bih_gz = (const float*)d_in[8];
  const float* bhh_gz = (const float*)d_in[9];
  const float* W0     = (const float*)d_in[10];
  const float* b0     = (const float*)d_in[11];
  const float* Wm     = (const float*)d_in[12];
  const float* bm     = (const float*)d_in[13];
  const float* Wv     = (const float*)d_in[14];
  const float* bv     = (const float*)d_in[15];
  const float* Wih_h  = (const float*)d_in[16];
  const float* Whh_h  = (const float*)d_in[17];
  const float* bih_h  = (const float*)d_in[18];
  const float* bhh_h  = (const float*)d_in[19];
  const float* Wy     = (const float*)d_in[20];
  const float* by     = (const float*)d_in[21];

  char* ws = (char*)d_ws;
  float*    wT   = (float*)(ws + 0);                 // 526,336 B
  float*    wyT  = (float*)(ws + 526336);            // 131,584 B
  uint4*    pkw  = (uint4*)(ws + 1048576);           // 532,480 B packed frags
  uint16_t* px   = (uint16_t*)(ws + 2097152);        // bf16 T*B*512 = 134,217,728 B
  uint16_t* gx   = (uint16_t*)(ws + 136314880);      // bf16 T*B*128 = 33,554,432 B
  uint16_t* zbuf = (uint16_t*)(ws + 169869312);      // bf16 T*B*16  =  4,194,304 B
  uint16_t* hdec = (uint16_t*)(ws + 174063616);      // bf16 T*B*128 = 33,554,432 B
  // end 207,618,048 B

  float* out_y      = (float*)d_out;                         // (B,257,T)
  float* out_mean   = out_y + (size_t)BATCH * XD * T_SEQ;    // (B,16,T)
  float* out_logvar = out_mean + (size_t)BATCH * ZD * T_SEQ;
  float* out_z      = out_logvar + (size_t)BATCH * ZD * T_SEQ;

  k_prep<<<dim3(643), dim3(256), 0, stream>>>(Wih_gx, Wy, wT, wyT);
  k_pack<<<dim3((NPACK + 255) / 256), dim3(256), 0, stream>>>(
      Whh_gx, Whh_gz, Whh_h, Wih_gz, Wih_h, W0, Wm, Wv, pkw);
  k_proj<<<dim3(8, 256), dim3(256), 0, stream>>>(x, wT, bih_gx, bhh_gx, px);
  k_lstm_gx<<<dim3(16), dim3(512), 0, stream>>>(px, pkw, gx);
  k_inf<<<dim3(16), dim3(512), 0, stream>>>(gx, eps, pkw, bih_gz, bhh_gz,
                                            b0, bm, bv, zbuf, out_mean, out_logvar, out_z);
  k_dec<<<dim3(16), dim3(512), 0, stream>>>(zbuf, pkw, bih_h, bhh_h, hdec);
  k_y<<<dim3(8, 256), dim3(256), 0, stream>>>(hdec, wyT, by, out_y);
}